// Round 8
// baseline (538.365 us; speedup 1.0000x reference)
//
#include <hip/hip_runtime.h>

#define FDIM 128
#define HDIM 64
#define MSIZE 64
#define IMG_W 56
#define IMG_H 56
#define NPIX (IMG_W * IMG_H)
#define NB 8
#define NPTS 65536

typedef _Float16 f16x8 __attribute__((ext_vector_type(8)));
typedef __fp16 hf16x2 __attribute__((ext_vector_type(2)));   // return type of cvt_pkrtz
typedef float f32x4 __attribute__((ext_vector_type(4)));
typedef int i32x4 __attribute__((ext_vector_type(4)));

// d_ws layout:
//   [0, 32768)       : W1 fragments fp16 (8kt*4nt*64lane*8)
//   [32768, 40960)   : W2 fragments
//   [40960, 49152)   : W3 fragments
//   [49152, 49216)   : barrier counters (9 ints used; memset to 0 pre-launch)
//   [49664, +6.4MB)  : transposed features (B, H*W, C) fp16
#define W2_OFF 16384   // in halves
#define W3_OFF 20480
#define CNT_OFF 49152
#define FT_BYTE_OFF 49664

// wave-local LDS fence
__device__ __forceinline__ void lds_fence() {
    __asm__ volatile("s_waitcnt lgkmcnt(0)" ::: "memory");
}

// ============ single persistent kernel: prep + device barrier + decode ============
// Grid = 1024 blocks x 256 thr. launch_bounds(256,4) -> VGPR<=128 -> >=4 blocks/CU
// -> capacity >= 1024 = grid -> all blocks co-resident -> barrier cannot deadlock.
// Block g: batch b=g&7, sub=g>>3 (0..127 per batch).
//   prep: sub<49 transposes 64px x 128ch of plane b (fp32 CHW -> fp16 HWC);
//         g<12 packs weight fragments. Then signal cnt[b] (target 128) / cnt[8] (12).
//   barrier: spin on own batch counter + pack counter (device-scope atomics,
//            __threadfence for cross-XCD L2 writeback/invalidate).
//   decode: 4 iterations of the R7-verified 4-wave/32-pt decode body.
__global__ __launch_bounds__(256, 4) void fused_all(
    const float* __restrict__ feats, const float* __restrict__ points,
    const float* __restrict__ Kmat, const float* __restrict__ Rt,
    const float* __restrict__ Bg,
    const float* __restrict__ W1, const float* __restrict__ W2,
    const float* __restrict__ W3,
    const float* __restrict__ b1, const float* __restrict__ b2,
    const float* __restrict__ b3,
    const float* __restrict__ W4, const float* __restrict__ b4,
    _Float16* __restrict__ ws, float* __restrict__ out) {
    __shared__ __align__(16) char smem[4 * 32 * 72 * 2];   // 18432 B, reused prep/decode
    int* cnt = (int*)((char*)ws + CNT_OFF);
    _Float16* ft = (_Float16*)((char*)ws + FT_BYTE_OFF);
    const int g   = blockIdx.x;
    const int tid = threadIdx.x;
    const int b   = g & 7;
    const int sub = g >> 3;

    // ---------- prep A: weight pack (blocks 0..11) ----------
    if (g < 12) {
        const int t = g * 256 + tid;  // 0..3071
        const int l = t & 63;
        const int q = l >> 4;
        const int col = l & 15;
        const int frag = t >> 6;  // 0..47
        if (frag < 32) {
            const int kt = frag >> 2, nt = frag & 3;
#pragma unroll
            for (int j = 0; j < 8; ++j) {
                int k = kt * 32 + q * 8 + j;
                int row = (k < 128) ? k : (128 + (k & 1) * 64 + ((k - 128) >> 1));
                ws[((size_t)(frag * 64 + l)) * 8 + j] = (_Float16)W1[row * HDIM + nt * 16 + col];
            }
        } else if (frag < 40) {
            const int f2 = frag - 32;
            const int kt = f2 >> 2, nt = f2 & 3;
#pragma unroll
            for (int j = 0; j < 8; ++j) {
                int row = kt * 32 + q * 8 + j;
                ws[W2_OFF + ((size_t)(f2 * 64 + l)) * 8 + j] = (_Float16)W2[row * HDIM + nt * 16 + col];
            }
        } else {
            const int f3 = frag - 40;
            const int kt = f3 >> 2, nt = f3 & 3;
#pragma unroll
            for (int j = 0; j < 8; ++j) {
                int row = kt * 32 + q * 8 + j;
                ws[W3_OFF + ((size_t)(f3 * 64 + l)) * 8 + j] = (_Float16)W3[row * HDIM + nt * 16 + col];
            }
        }
    }

    // ---------- prep B: transpose macro-tile (sub<49: 64px x 128ch, 4 sub-tiles) ----------
    if (sub < 49) {
        float (*tile)[133] = (float (*)[133])smem;
        const float* src = feats + (size_t)b * FDIM * NPIX;
        _Float16*    dst = ft + (size_t)b * NPIX * FDIM;
        const int pq = tid & 3;
        const int ch = tid >> 2;
        const int px = tid >> 4;
        const int hk = (tid & 15) * 8;
#pragma unroll 1
        for (int st = 0; st < 4; ++st) {
            const int pbase = sub * 64 + st * 16;
            __syncthreads();   // protect tile reuse
#pragma unroll
            for (int it = 0; it < 2; ++it) {
                const int c = it * 64 + ch;
                const float4 v = *(const float4*)(src + (size_t)c * NPIX + pbase + pq * 4);
                tile[pq * 4 + 0][c] = v.x;
                tile[pq * 4 + 1][c] = v.y;
                tile[pq * 4 + 2][c] = v.z;
                tile[pq * 4 + 3][c] = v.w;
            }
            __syncthreads();
            union { f16x8 v; hf16x2 h[4]; } hv;
#pragma unroll
            for (int j = 0; j < 4; ++j)
                hv.h[j] = __builtin_amdgcn_cvt_pkrtz(tile[px][hk + 2 * j], tile[px][hk + 2 * j + 1]);
            *(f16x8*)(dst + (size_t)(pbase + px) * FDIM + hk) = hv.v;
        }
    }

    // ---------- device-scope barrier ----------
    __syncthreads();
    __threadfence();           // release: drain + make ft/wfrag visible device-wide
    if (tid == 0) {
        atomicAdd(&cnt[b], 1);
        if (g < 12) atomicAdd(&cnt[8], 1);
    }
    if (tid == 0) {
        while (atomicAdd(&cnt[b], 0) < 128 || atomicAdd(&cnt[8], 0) < 12)
            __builtin_amdgcn_s_sleep(2);
    }
    __syncthreads();
    __threadfence();           // acquire: invalidate caches before reading ft/wfrag

    // ---------- decode: 4 iterations of R7-verified body ----------
    const _Float16* wfrag = ws;
    const int wid = tid >> 6;
    const int l   = tid & 63;
    const int q   = l >> 4;
    const int col = l & 15;
    _Float16* Ah = (_Float16*)smem + wid * 32 * 72;
    float* sh = (float*)Ah;
    int*   shi = (int*)Ah;
    const f32x4 zero4 = {0.0f, 0.0f, 0.0f, 0.0f};

#pragma unroll 1
    for (int iter = 0; iter < 4; ++iter) {
        const int grp  = sub * 4 + iter;             // 0..511 per batch
        const int base = b * NPTS + grp * 128 + wid * 32;
        lds_fence();

        // ---- lanes 0..31: projection + bilinear record (verified fp32 chain) ----
        if (l < 32) {
            const int gid = base + l;
            const float px = points[(size_t)gid * 3 + 0];
            const float py = points[(size_t)gid * 3 + 1];
            const float pz = points[(size_t)gid * 3 + 2];
            const float* rt = Rt + b * 12;
            const float* km = Kmat + b * 9;
            float cx = rt[0] * px + rt[1] * py + rt[2]  * pz + rt[3];
            float cy = rt[4] * px + rt[5] * py + rt[6]  * pz + rt[7];
            float cz = rt[8] * px + rt[9] * py + rt[10] * pz + rt[11];
            float ix = km[0] * cx + km[1] * cy + km[2] * cz;
            float iy = km[3] * cx + km[4] * cy + km[5] * cz;
            float iz = km[6] * cx + km[7] * cy + km[8] * cz;
            float z  = iz + 1e-8f;
            float u  = ix / z;
            float v  = iy / z;
            float valid = (iz > 0.0f) ? 1.0f : 0.0f;
            float u_norm = (2.0f * u + 1.0f) / (float)IMG_W - 1.0f;
            float v_norm = (2.0f * v + 1.0f) / (float)IMG_H - 1.0f;
            float x = ((u_norm + 1.0f) * (float)IMG_W - 1.0f) * 0.5f;
            float y = ((v_norm + 1.0f) * (float)IMG_H - 1.0f) * 0.5f;
            float x0f = floorf(x), y0f = floorf(y);
            float wx1 = x - x0f, wy1 = y - y0f;
            float wx0 = 1.0f - wx1, wy0 = 1.0f - wy1;
            int x0 = (int)x0f, y0 = (int)y0f;
            int x1 = x0 + 1, y1 = y0 + 1;
            int x0c = x0 < 0 ? 0 : (x0 > IMG_W - 1 ? IMG_W - 1 : x0);
            int x1c = x1 < 0 ? 0 : (x1 > IMG_W - 1 ? IMG_W - 1 : x1);
            int y0c = y0 < 0 ? 0 : (y0 > IMG_H - 1 ? IMG_H - 1 : y0);
            int y1c = y1 < 0 ? 0 : (y1 > IMG_H - 1 ? IMG_H - 1 : y1);
            float mx0 = (x0 >= 0 && x0 < IMG_W) ? 1.0f : 0.0f;
            float mx1 = (x1 >= 0 && x1 < IMG_W) ? 1.0f : 0.0f;
            float my0 = (y0 >= 0 && y0 < IMG_H) ? 1.0f : 0.0f;
            float my1 = (y1 >= 0 && y1 < IMG_H) ? 1.0f : 0.0f;
            const int pb = b * NPIX;
            sh[l * 12 + 0] = wx0 * wy0 * mx0 * my0 * valid;
            sh[l * 12 + 1] = wx1 * wy0 * mx1 * my0 * valid;
            sh[l * 12 + 2] = wx0 * wy1 * mx0 * my1 * valid;
            sh[l * 12 + 3] = wx1 * wy1 * mx1 * my1 * valid;
            shi[l * 12 + 4] = (pb + y0c * IMG_W + x0c) * FDIM;
            shi[l * 12 + 5] = (pb + y0c * IMG_W + x1c) * FDIM;
            shi[l * 12 + 6] = (pb + y1c * IMG_W + x0c) * FDIM;
            shi[l * 12 + 7] = (pb + y1c * IMG_W + x1c) * FDIM;
            sh[l * 12 + 8]  = px;
            sh[l * 12 + 9]  = py;
            sh[l * 12 + 10] = pz;
        }
        lds_fence();

        f32x4 acc[2][4];
#pragma unroll
        for (int mt = 0; mt < 2; ++mt)
#pragma unroll
            for (int nt = 0; nt < 4; ++nt) acc[mt][nt] = zero4;

        f32x4 wv[2];
        i32x4 iv[2];
        float qx[2], qy[2], qz[2];
#pragma unroll
        for (int mt = 0; mt < 2; ++mt) {
            const float* e = sh + (mt * 16 + col) * 12;
            wv[mt] = *(const f32x4*)(e);
            iv[mt] = *(const i32x4*)(e + 4);
            qx[mt] = e[8]; qy[mt] = e[9]; qz[mt] = e[10];
        }

        // pre-issue first corner-load group
        f16x8 c00 = *(const f16x8*)(ft + iv[0].x + q * 8);
        f16x8 c10 = *(const f16x8*)(ft + iv[0].y + q * 8);
        f16x8 c01 = *(const f16x8*)(ft + iv[0].z + q * 8);
        f16x8 c11 = *(const f16x8*)(ft + iv[0].w + q * 8);

        // ====== Phase F: Fourier k-tiles 4..7 ======
#pragma unroll
        for (int ktf = 0; ktf < 4; ++ktf) {
            float bgx[4], bgy[4], bgz[4];
#pragma unroll
            for (int i = 0; i < 4; ++i) {
                const int m = ktf * 16 + q * 4 + i;
                bgx[i] = Bg[m * 3 + 0];
                bgy[i] = Bg[m * 3 + 1];
                bgz[i] = Bg[m * 3 + 2];
            }
            f16x8 bf[4];
#pragma unroll
            for (int nt = 0; nt < 4; ++nt)
                bf[nt] = *(const f16x8*)(wfrag + ((size_t)(((4 + ktf) * 4 + nt) * 64 + l)) * 8);
#pragma unroll
            for (int mt = 0; mt < 2; ++mt) {
                union { f16x8 v; hf16x2 h[4]; } af;
#pragma unroll
                for (int i = 0; i < 4; ++i) {
                    float t = bgx[i] * qx[mt] + bgy[i] * qy[mt] + bgz[i] * qz[mt];
                    float tf = __builtin_amdgcn_fractf(t);
                    af.h[i] = __builtin_amdgcn_cvt_pkrtz(__builtin_amdgcn_sinf(tf),
                                                         __builtin_amdgcn_cosf(tf));
                }
#pragma unroll
                for (int nt = 0; nt < 4; ++nt)
                    acc[mt][nt] = __builtin_amdgcn_mfma_f32_16x16x32_f16(af.v, bf[nt], acc[mt][nt], 0, 0, 0);
            }
        }

        // ====== Phase I: image k-tiles, packed-fp16 blend, depth-1 prefetch ======
        _Float16 wh[2][4];
#pragma unroll
        for (int mt = 0; mt < 2; ++mt) {
            wh[mt][0] = (_Float16)wv[mt].x; wh[mt][1] = (_Float16)wv[mt].y;
            wh[mt][2] = (_Float16)wv[mt].z; wh[mt][3] = (_Float16)wv[mt].w;
        }
#pragma unroll
        for (int s = 0; s < 8; ++s) {
            const int mt = s >> 2, ktg = s & 3;
            f16x8 n00, n10, n01, n11;
            if (s < 7) {
                const int nmt = (s + 1) >> 2, nktg = (s + 1) & 3;
                const int co = nktg * 32 + q * 8;
                n00 = *(const f16x8*)(ft + iv[nmt].x + co);
                n10 = *(const f16x8*)(ft + iv[nmt].y + co);
                n01 = *(const f16x8*)(ft + iv[nmt].z + co);
                n11 = *(const f16x8*)(ft + iv[nmt].w + co);
            }
            f16x8 af = c00 * wh[mt][0] + c10 * wh[mt][1] + c01 * wh[mt][2] + c11 * wh[mt][3];
#pragma unroll
            for (int nt = 0; nt < 4; ++nt) {
                f16x8 bf = *(const f16x8*)(wfrag + ((size_t)((ktg * 4 + nt) * 64 + l)) * 8);
                acc[mt][nt] = __builtin_amdgcn_mfma_f32_16x16x32_f16(af, bf, acc[mt][nt], 0, 0, 0);
            }
            c00 = n00; c10 = n10; c01 = n01; c11 = n11;
        }

        // ---- L1 epilogue ----
        float bb[4];
#pragma unroll
        for (int nt = 0; nt < 4; ++nt) bb[nt] = b1[nt * 16 + col];
#pragma unroll
        for (int mt = 0; mt < 2; ++mt)
#pragma unroll
            for (int nt = 0; nt < 4; ++nt)
#pragma unroll
                for (int r = 0; r < 4; ++r) {
                    float hv = fmaxf(acc[mt][nt][r] + bb[nt], 0.0f);
                    Ah[(mt * 16 + q * 4 + r) * 72 + nt * 16 + col] = (_Float16)hv;
                }
        lds_fence();

        // ---- layer 2 ----
#pragma unroll
        for (int mt = 0; mt < 2; ++mt)
#pragma unroll
            for (int nt = 0; nt < 4; ++nt) acc[mt][nt] = zero4;
#pragma unroll
        for (int ktl = 0; ktl < 2; ++ktl) {
            f16x8 bf[4];
#pragma unroll
            for (int nt = 0; nt < 4; ++nt)
                bf[nt] = *(const f16x8*)(wfrag + W2_OFF + ((size_t)((ktl * 4 + nt) * 64 + l)) * 8);
#pragma unroll
            for (int mt = 0; mt < 2; ++mt) {
                f16x8 af = *(const f16x8*)(&Ah[(mt * 16 + col) * 72 + ktl * 32 + q * 8]);
#pragma unroll
                for (int nt = 0; nt < 4; ++nt)
                    acc[mt][nt] = __builtin_amdgcn_mfma_f32_16x16x32_f16(af, bf[nt], acc[mt][nt], 0, 0, 0);
            }
        }
        lds_fence();
#pragma unroll
        for (int nt = 0; nt < 4; ++nt) bb[nt] = b2[nt * 16 + col];
#pragma unroll
        for (int mt = 0; mt < 2; ++mt)
#pragma unroll
            for (int nt = 0; nt < 4; ++nt)
#pragma unroll
                for (int r = 0; r < 4; ++r) {
                    float hv = fmaxf(acc[mt][nt][r] + bb[nt], 0.0f);
                    Ah[(mt * 16 + q * 4 + r) * 72 + nt * 16 + col] = (_Float16)hv;
                }
        lds_fence();

        // ---- layer 3 ----
#pragma unroll
        for (int mt = 0; mt < 2; ++mt)
#pragma unroll
            for (int nt = 0; nt < 4; ++nt) acc[mt][nt] = zero4;
#pragma unroll
        for (int ktl = 0; ktl < 2; ++ktl) {
            f16x8 bf[4];
#pragma unroll
            for (int nt = 0; nt < 4; ++nt)
                bf[nt] = *(const f16x8*)(wfrag + W3_OFF + ((size_t)((ktl * 4 + nt) * 64 + l)) * 8);
#pragma unroll
            for (int mt = 0; mt < 2; ++mt) {
                f16x8 af = *(const f16x8*)(&Ah[(mt * 16 + col) * 72 + ktl * 32 + q * 8]);
#pragma unroll
                for (int nt = 0; nt < 4; ++nt)
                    acc[mt][nt] = __builtin_amdgcn_mfma_f32_16x16x32_f16(af, bf[nt], acc[mt][nt], 0, 0, 0);
            }
        }

        // ---- layer 4 ----
        float b3v[4], w4v[4];
#pragma unroll
        for (int nt = 0; nt < 4; ++nt) {
            b3v[nt] = b3[nt * 16 + col];
            w4v[nt] = W4[nt * 16 + col];
        }
        const float b4v = b4[0];
#pragma unroll
        for (int mt = 0; mt < 2; ++mt)
#pragma unroll
            for (int r = 0; r < 4; ++r) {
                float p = 0.0f;
#pragma unroll
                for (int nt = 0; nt < 4; ++nt)
                    p = fmaf(fmaxf(acc[mt][nt][r] + b3v[nt], 0.0f), w4v[nt], p);
                p += __shfl_xor(p, 1);
                p += __shfl_xor(p, 2);
                p += __shfl_xor(p, 4);
                p += __shfl_xor(p, 8);
                if (col == 0) out[base + mt * 16 + q * 4 + r] = p + b4v;
            }
    }
}

// ---------------- fallback: verified R1 pure-VALU kernel ----------------
__global__ __launch_bounds__(64, 2) void decoder_valu(
    const float* __restrict__ feats, const float* __restrict__ points,
    const float* __restrict__ Kmat, const float* __restrict__ Rt,
    const float* __restrict__ Bg,
    const float* __restrict__ W1, const float* __restrict__ b1,
    const float* __restrict__ W2, const float* __restrict__ b2,
    const float* __restrict__ W3, const float* __restrict__ b3,
    const float* __restrict__ W4, const float* __restrict__ b4,
    float* __restrict__ out) {
    __shared__ float hbuf[64 * 65];
    const int tid = threadIdx.x;
    const int b   = blockIdx.x / (NPTS / 64);
    const int gid = blockIdx.x * 64 + tid;
    const float px = points[(size_t)gid * 3 + 0];
    const float py = points[(size_t)gid * 3 + 1];
    const float pz = points[(size_t)gid * 3 + 2];
    const float* rt = Rt + b * 12;
    const float* km = Kmat + b * 9;
    float cx = rt[0] * px + rt[1] * py + rt[2]  * pz + rt[3];
    float cy = rt[4] * px + rt[5] * py + rt[6]  * pz + rt[7];
    float cz = rt[8] * px + rt[9] * py + rt[10] * pz + rt[11];
    float ix = km[0] * cx + km[1] * cy + km[2] * cz;
    float iy = km[3] * cx + km[4] * cy + km[5] * cz;
    float iz = km[6] * cx + km[7] * cy + km[8] * cz;
    float z  = iz + 1e-8f;
    float u  = ix / z, v = iy / z;
    float valid = (iz > 0.0f) ? 1.0f : 0.0f;
    float u_norm = (2.0f * u + 1.0f) / (float)IMG_W - 1.0f;
    float v_norm = (2.0f * v + 1.0f) / (float)IMG_H - 1.0f;
    float x = ((u_norm + 1.0f) * (float)IMG_W - 1.0f) * 0.5f;
    float y = ((v_norm + 1.0f) * (float)IMG_H - 1.0f) * 0.5f;
    float x0f = floorf(x), y0f = floorf(y);
    float wx1 = x - x0f, wy1 = y - y0f;
    float wx0 = 1.0f - wx1, wy0 = 1.0f - wy1;
    int x0 = (int)x0f, y0 = (int)y0f;
    int x1 = x0 + 1, y1 = y0 + 1;
    int x0c = x0 < 0 ? 0 : (x0 > IMG_W - 1 ? IMG_W - 1 : x0);
    int x1c = x1 < 0 ? 0 : (x1 > IMG_W - 1 ? IMG_W - 1 : x1);
    int y0c = y0 < 0 ? 0 : (y0 > IMG_H - 1 ? IMG_H - 1 : y0);
    int y1c = y1 < 0 ? 0 : (y1 > IMG_H - 1 ? IMG_H - 1 : y1);
    float mx0 = (x0 >= 0 && x0 < IMG_W) ? 1.0f : 0.0f;
    float mx1 = (x1 >= 0 && x1 < IMG_W) ? 1.0f : 0.0f;
    float my0 = (y0 >= 0 && y0 < IMG_H) ? 1.0f : 0.0f;
    float my1 = (y1 >= 0 && y1 < IMG_H) ? 1.0f : 0.0f;
    float w00 = wx0 * wy0 * mx0 * my0 * valid;
    float w10 = wx1 * wy0 * mx1 * my0 * valid;
    float w01 = wx0 * wy1 * mx0 * my1 * valid;
    float w11 = wx1 * wy1 * mx1 * my1 * valid;
    float h[HDIM];
#pragma unroll
    for (int j = 0; j < HDIM; ++j) h[j] = b1[j];
    const float* fb = feats + (size_t)b * FDIM * NPIX;
    const int p00 = y0c * IMG_W + x0c, p10 = y0c * IMG_W + x1c;
    const int p01 = y1c * IMG_W + x0c, p11 = y1c * IMG_W + x1c;
#pragma unroll 1
    for (int c = 0; c < FDIM; ++c) {
        const float* fp = fb + (size_t)c * NPIX;
        float fv = w00 * fp[p00] + w10 * fp[p10] + w01 * fp[p01] + w11 * fp[p11];
        const float* wr = W1 + (size_t)c * HDIM;
#pragma unroll
        for (int j = 0; j < HDIM; ++j) h[j] = fmaf(fv, wr[j], h[j]);
    }
#pragma unroll 1
    for (int m = 0; m < MSIZE; ++m) {
        float t = Bg[m * 3 + 0] * px + Bg[m * 3 + 1] * py + Bg[m * 3 + 2] * pz;
        float tf = t - floorf(t);
        float s = __builtin_amdgcn_sinf(tf);
        float c = __builtin_amdgcn_cosf(tf);
        const float* wsn = W1 + (size_t)(FDIM + m) * HDIM;
        const float* wcs = W1 + (size_t)(FDIM + MSIZE + m) * HDIM;
#pragma unroll
        for (int j = 0; j < HDIM; ++j)
            h[j] = fmaf(s, wsn[j], fmaf(c, wcs[j], h[j]));
    }
    float* myh = &hbuf[tid * 65];
#pragma unroll
    for (int j = 0; j < HDIM; ++j) myh[j] = fmaxf(h[j], 0.0f);
    float h2[HDIM];
#pragma unroll
    for (int j = 0; j < HDIM; ++j) h2[j] = b2[j];
#pragma unroll 1
    for (int i = 0; i < HDIM; ++i) {
        float hi = myh[i];
        const float* wr = W2 + (size_t)i * HDIM;
#pragma unroll
        for (int j = 0; j < HDIM; ++j) h2[j] = fmaf(hi, wr[j], h2[j]);
    }
#pragma unroll
    for (int j = 0; j < HDIM; ++j) myh[j] = fmaxf(h2[j], 0.0f);
#pragma unroll
    for (int j = 0; j < HDIM; ++j) h[j] = b3[j];
#pragma unroll 1
    for (int i = 0; i < HDIM; ++i) {
        float hi = myh[i];
        const float* wr = W3 + (size_t)i * HDIM;
#pragma unroll
        for (int j = 0; j < HDIM; ++j) h[j] = fmaf(hi, wr[j], h[j]);
    }
    float acc = b4[0];
#pragma unroll
    for (int j = 0; j < HDIM; ++j) acc = fmaf(fmaxf(h[j], 0.0f), W4[j], acc);
    out[gid] = acc;
}

extern "C" void kernel_launch(void* const* d_in, const int* in_sizes, int n_in,
                              void* d_out, int out_size, void* d_ws, size_t ws_size,
                              hipStream_t stream) {
    const float* feats = (const float*)d_in[0];
    const float* pts   = (const float*)d_in[1];
    const float* k     = (const float*)d_in[2];
    const float* rt    = (const float*)d_in[3];
    const float* Bg    = (const float*)d_in[4];
    const float* W1    = (const float*)d_in[5];
    const float* b1    = (const float*)d_in[6];
    const float* W2    = (const float*)d_in[7];
    const float* b2    = (const float*)d_in[8];
    const float* W3    = (const float*)d_in[9];
    const float* b3    = (const float*)d_in[10];
    const float* W4    = (const float*)d_in[11];
    const float* b4    = (const float*)d_in[12];
    float* out = (float*)d_out;

    const size_t ftBytes = (size_t)NB * NPIX * FDIM * sizeof(_Float16);

    if (ws_size >= FT_BYTE_OFF + ftBytes) {
        _Float16* wf = (_Float16*)d_ws;
        hipMemsetAsync((char*)d_ws + CNT_OFF, 0, 64, stream);
        fused_all<<<1024, 256, 0, stream>>>(feats, pts, k, rt, Bg, W1, W2, W3,
                                            b1, b2, b3, W4, b4, wf, out);
    } else {
        decoder_valu<<<NB * NPTS / 64, 64, 0, stream>>>(feats, pts, k, rt, Bg,
                                                        W1, b1, W2, b2, W3, b3, W4, b4, out);
    }
}

// Round 9
// 183.987 us; speedup vs baseline: 2.9261x; 2.9261x over previous
//
#include <hip/hip_runtime.h>

#define FDIM 128
#define HDIM 64
#define MSIZE 64
#define IMG_W 56
#define IMG_H 56
#define NPIX (IMG_W * IMG_H)
#define NB 8
#define NPTS 65536

typedef _Float16 f16x8 __attribute__((ext_vector_type(8)));
typedef __fp16 hf16x2 __attribute__((ext_vector_type(2)));   // return type of cvt_pkrtz
typedef float f32x4 __attribute__((ext_vector_type(4)));

// d_ws layout:
//   [0, 32768)     : W1 fragments fp16 (8kt*4nt*64lane*8)
//   [32768, 40960) : W2 fragments
//   [40960, 49152) : W3 fragments
//   [49152, +6.4MB): transposed features (B, H*W, C) fp16
#define W2_OFF 16384   // in halves
#define W3_OFF 20480
#define FT_BYTE_OFF 49152
#define TR16_BLOCKS (NPIX / 16 * NB)   // 1568

// wave-local LDS fence: orders this wave's ds ops without the full
// vmcnt(0)+barrier drain __syncthreads forces.
__device__ __forceinline__ void lds_fence() {
    __asm__ volatile("s_waitcnt lgkmcnt(0)" ::: "memory");
}

// ---- fused prep (R7-verified): transpose + weight pack ----
__global__ __launch_bounds__(256) void prep_kernel(const float* __restrict__ in,
                                                   const float* __restrict__ W1,
                                                   const float* __restrict__ W2,
                                                   const float* __restrict__ W3,
                                                   _Float16* __restrict__ ws) {
    if (blockIdx.x < TR16_BLOCKS) {
        __shared__ float tile[16][133];
        _Float16* out = ws + FT_BYTE_OFF / 2;
        const int b = blockIdx.x / (NPIX / 16);
        const int pbase = (blockIdx.x % (NPIX / 16)) * 16;
        const int t = threadIdx.x;
        const float* src = in + (size_t)b * FDIM * NPIX;
        _Float16*    dst = out + (size_t)b * NPIX * FDIM;
        const int pq = t & 3;
        const int ch = t >> 2;
#pragma unroll
        for (int it = 0; it < 2; ++it) {
            const int c = it * 64 + ch;
            const float4 v = *(const float4*)(src + (size_t)c * NPIX + pbase + pq * 4);
            tile[pq * 4 + 0][c] = v.x;
            tile[pq * 4 + 1][c] = v.y;
            tile[pq * 4 + 2][c] = v.z;
            tile[pq * 4 + 3][c] = v.w;
        }
        __syncthreads();
        const int px = t >> 4;
        const int hk = (t & 15) * 8;
        union { f16x8 v; hf16x2 h[4]; } hv;
#pragma unroll
        for (int j = 0; j < 4; ++j)
            hv.h[j] = __builtin_amdgcn_cvt_pkrtz(tile[px][hk + 2 * j], tile[px][hk + 2 * j + 1]);
        *(f16x8*)(dst + (size_t)(pbase + px) * FDIM + hk) = hv.v;
    } else {
        const int t = (blockIdx.x - TR16_BLOCKS) * 256 + threadIdx.x;  // 0..3071
        const int l = t & 63;
        const int q = l >> 4;
        const int col = l & 15;
        const int frag = t >> 6;  // 0..47
        if (frag < 32) {
            const int kt = frag >> 2, nt = frag & 3;
#pragma unroll
            for (int j = 0; j < 8; ++j) {
                int k = kt * 32 + q * 8 + j;
                int row = (k < 128) ? k : (128 + (k & 1) * 64 + ((k - 128) >> 1));
                ws[((size_t)(frag * 64 + l)) * 8 + j] = (_Float16)W1[row * HDIM + nt * 16 + col];
            }
        } else if (frag < 40) {
            const int f2 = frag - 32;
            const int kt = f2 >> 2, nt = f2 & 3;
#pragma unroll
            for (int j = 0; j < 8; ++j) {
                int row = kt * 32 + q * 8 + j;
                ws[W2_OFF + ((size_t)(f2 * 64 + l)) * 8 + j] = (_Float16)W2[row * HDIM + nt * 16 + col];
            }
        } else {
            const int f3 = frag - 40;
            const int kt = f3 >> 2, nt = f3 & 3;
#pragma unroll
            for (int j = 0; j < 8; ++j) {
                int row = kt * 32 + q * 8 + j;
                ws[W3_OFF + ((size_t)(f3 * 64 + l)) * 8 + j] = (_Float16)W3[row * HDIM + nt * 16 + col];
            }
        }
    }
}

// ---------------- decoder v4: shfl records, depth-2 prefetch, reg-prefetched W2/W3 ----------------
__global__ __launch_bounds__(256, 3) void decoder_mfma4(
    const _Float16* __restrict__ ft,   // (B, HW, C) fp16
    const float* __restrict__ points,
    const float* __restrict__ Kmat, const float* __restrict__ Rt,
    const float* __restrict__ Bg,
    const _Float16* __restrict__ wfrag,
    const float* __restrict__ b1, const float* __restrict__ b2,
    const float* __restrict__ b3,
    const float* __restrict__ W4, const float* __restrict__ b4,
    float* __restrict__ out) {
    __shared__ _Float16 lds[4 * 32 * 72];   // 18432 B, A/H tile only (records via shfl)
    const int tid = threadIdx.x;
    const int wid = tid >> 6;
    const int l   = tid & 63;
    const int q   = l >> 4;
    const int col = l & 15;
    const int b    = blockIdx.x & 7;             // XCD swizzle: batch plane per XCD L2
    const int grp  = blockIdx.x >> 3;            // 0..511
    const int base = b * NPTS + grp * 128 + wid * 32;
    _Float16* Ah = lds + wid * 32 * 72;

    // ---- ALL lanes: projection for point base + (l&31); lanes 32..63 duplicate ----
    {
        const int gid = base + (l & 31);
        const float px = points[(size_t)gid * 3 + 0];
        const float py = points[(size_t)gid * 3 + 1];
        const float pz = points[(size_t)gid * 3 + 2];
        const float* rt = Rt + b * 12;
        const float* km = Kmat + b * 9;
        float cx = rt[0] * px + rt[1] * py + rt[2]  * pz + rt[3];
        float cy = rt[4] * px + rt[5] * py + rt[6]  * pz + rt[7];
        float cz = rt[8] * px + rt[9] * py + rt[10] * pz + rt[11];
        float ix = km[0] * cx + km[1] * cy + km[2] * cz;
        float iy = km[3] * cx + km[4] * cy + km[5] * cz;
        float iz = km[6] * cx + km[7] * cy + km[8] * cz;
        float z  = iz + 1e-8f;
        float u  = ix / z;
        float v  = iy / z;
        float valid = (iz > 0.0f) ? 1.0f : 0.0f;
        float u_norm = (2.0f * u + 1.0f) / (float)IMG_W - 1.0f;
        float v_norm = (2.0f * v + 1.0f) / (float)IMG_H - 1.0f;
        float x = ((u_norm + 1.0f) * (float)IMG_W - 1.0f) * 0.5f;
        float y = ((v_norm + 1.0f) * (float)IMG_H - 1.0f) * 0.5f;
        float x0f = floorf(x), y0f = floorf(y);
        float wx1 = x - x0f, wy1 = y - y0f;
        float wx0 = 1.0f - wx1, wy0 = 1.0f - wy1;
        int x0 = (int)x0f, y0 = (int)y0f;
        int x1 = x0 + 1, y1 = y0 + 1;
        int x0c = x0 < 0 ? 0 : (x0 > IMG_W - 1 ? IMG_W - 1 : x0);
        int x1c = x1 < 0 ? 0 : (x1 > IMG_W - 1 ? IMG_W - 1 : x1);
        int y0c = y0 < 0 ? 0 : (y0 > IMG_H - 1 ? IMG_H - 1 : y0);
        int y1c = y1 < 0 ? 0 : (y1 > IMG_H - 1 ? IMG_H - 1 : y1);
        float mx0 = (x0 >= 0 && x0 < IMG_W) ? 1.0f : 0.0f;
        float mx1 = (x1 >= 0 && x1 < IMG_W) ? 1.0f : 0.0f;
        float my0 = (y0 >= 0 && y0 < IMG_H) ? 1.0f : 0.0f;
        float my1 = (y1 >= 0 && y1 < IMG_H) ? 1.0f : 0.0f;
        const int pb = b * NPIX;
        // own-point record in registers; broadcast below
        float r_w00 = wx0 * wy0 * mx0 * my0 * valid;
        float r_w10 = wx1 * wy0 * mx1 * my0 * valid;
        float r_w01 = wx0 * wy1 * mx0 * my1 * valid;
        float r_w11 = wx1 * wy1 * mx1 * my1 * valid;
        int r_i00 = (pb + y0c * IMG_W + x0c) * FDIM;
        int r_i10 = (pb + y0c * IMG_W + x1c) * FDIM;
        int r_i01 = (pb + y1c * IMG_W + x0c) * FDIM;
        int r_i11 = (pb + y1c * IMG_W + x1c) * FDIM;

        // ---- broadcast records: lane l reads point mt*16+col's record ----
        float wv0[2], wv1[2], wv2[2], wv3[2];
        int   iv0[2], iv1[2], iv2[2], iv3[2];
        float qx[2], qy[2], qz[2];
#pragma unroll
        for (int mt = 0; mt < 2; ++mt) {
            const int src = mt * 16 + col;
            wv0[mt] = __shfl(r_w00, src);
            wv1[mt] = __shfl(r_w10, src);
            wv2[mt] = __shfl(r_w01, src);
            wv3[mt] = __shfl(r_w11, src);
            iv0[mt] = __shfl(r_i00, src);
            iv1[mt] = __shfl(r_i10, src);
            iv2[mt] = __shfl(r_i01, src);
            iv3[mt] = __shfl(r_i11, src);
            qx[mt]  = __shfl(px, src);
            qy[mt]  = __shfl(py, src);
            qz[mt]  = __shfl(pz, src);
        }

        const f32x4 zero4 = {0.0f, 0.0f, 0.0f, 0.0f};
        f32x4 acc[2][4];
#pragma unroll
        for (int mt = 0; mt < 2; ++mt)
#pragma unroll
            for (int nt = 0; nt < 4; ++nt) acc[mt][nt] = zero4;

        // ---- pre-issue corner-load groups s=0 and s=1 (depth-2) ----
        const int co0 = q * 8;
        f16x8 a00 = *(const f16x8*)(ft + iv0[0] + co0);
        f16x8 a10 = *(const f16x8*)(ft + iv1[0] + co0);
        f16x8 a01 = *(const f16x8*)(ft + iv2[0] + co0);
        f16x8 a11 = *(const f16x8*)(ft + iv3[0] + co0);
        const int co1 = 32 + q * 8;
        f16x8 e00 = *(const f16x8*)(ft + iv0[0] + co1);
        f16x8 e10 = *(const f16x8*)(ft + iv1[0] + co1);
        f16x8 e01 = *(const f16x8*)(ft + iv2[0] + co1);
        f16x8 e11 = *(const f16x8*)(ft + iv3[0] + co1);

        // ====== Phase F: Fourier k-tiles 4..7 (hides gather latency) ======
#pragma unroll
        for (int ktf = 0; ktf < 4; ++ktf) {
            float bgx[4], bgy[4], bgz[4];
#pragma unroll
            for (int i = 0; i < 4; ++i) {
                const int m = ktf * 16 + q * 4 + i;
                bgx[i] = Bg[m * 3 + 0];
                bgy[i] = Bg[m * 3 + 1];
                bgz[i] = Bg[m * 3 + 2];
            }
            f16x8 bf[4];
#pragma unroll
            for (int nt = 0; nt < 4; ++nt)
                bf[nt] = *(const f16x8*)(wfrag + ((size_t)(((4 + ktf) * 4 + nt) * 64 + l)) * 8);
#pragma unroll
            for (int mt = 0; mt < 2; ++mt) {
                union { f16x8 v; hf16x2 h[4]; } af;
#pragma unroll
                for (int i = 0; i < 4; ++i) {
                    float t = bgx[i] * qx[mt] + bgy[i] * qy[mt] + bgz[i] * qz[mt];
                    float tf = __builtin_amdgcn_fractf(t);
                    af.h[i] = __builtin_amdgcn_cvt_pkrtz(__builtin_amdgcn_sinf(tf),
                                                         __builtin_amdgcn_cosf(tf));
                }
#pragma unroll
                for (int nt = 0; nt < 4; ++nt)
                    acc[mt][nt] = __builtin_amdgcn_mfma_f32_16x16x32_f16(af.v, bf[nt], acc[mt][nt], 0, 0, 0);
            }
        }

        // ====== Phase I: 8 groups, depth-2 rolling prefetch, packed-fp16 blend ======
        _Float16 wh[2][4];
#pragma unroll
        for (int mt = 0; mt < 2; ++mt) {
            wh[mt][0] = (_Float16)wv0[mt]; wh[mt][1] = (_Float16)wv1[mt];
            wh[mt][2] = (_Float16)wv2[mt]; wh[mt][3] = (_Float16)wv3[mt];
        }
#pragma unroll
        for (int s = 0; s < 8; ++s) {
            const int mt = s >> 2;
            f16x8 t00, t10, t01, t11;
            if (s < 6) {
                const int nmt = (s + 2) >> 2, nktg = (s + 2) & 3;
                const int co = nktg * 32 + q * 8;
                t00 = *(const f16x8*)(ft + iv0[nmt] + co);
                t10 = *(const f16x8*)(ft + iv1[nmt] + co);
                t01 = *(const f16x8*)(ft + iv2[nmt] + co);
                t11 = *(const f16x8*)(ft + iv3[nmt] + co);
            }
            f16x8 af = a00 * wh[mt][0] + a10 * wh[mt][1] + a01 * wh[mt][2] + a11 * wh[mt][3];
            const int ktg = s & 3;
#pragma unroll
            for (int nt = 0; nt < 4; ++nt) {
                f16x8 bf = *(const f16x8*)(wfrag + ((size_t)((ktg * 4 + nt) * 64 + l)) * 8);
                acc[mt][nt] = __builtin_amdgcn_mfma_f32_16x16x32_f16(af, bf, acc[mt][nt], 0, 0, 0);
            }
            a00 = e00; a10 = e10; a01 = e01; a11 = e11;
            e00 = t00; e10 = t10; e01 = t01; e11 = t11;
        }

        // ---- prefetch W2 fragments (independent of epilogue/fence) ----
        f16x8 bfW[8];
#pragma unroll
        for (int f = 0; f < 8; ++f)
            bfW[f] = *(const f16x8*)(wfrag + W2_OFF + ((size_t)(f * 64 + l)) * 8);

        // ---- L1 epilogue: +b1, relu, store h1 in A-layout fp16 ----
        float bb[4];
#pragma unroll
        for (int nt = 0; nt < 4; ++nt) bb[nt] = b1[nt * 16 + col];
#pragma unroll
        for (int mt = 0; mt < 2; ++mt)
#pragma unroll
            for (int nt = 0; nt < 4; ++nt)
#pragma unroll
                for (int r = 0; r < 4; ++r) {
                    float hv = fmaxf(acc[mt][nt][r] + bb[nt], 0.0f);
                    Ah[(mt * 16 + q * 4 + r) * 72 + nt * 16 + col] = (_Float16)hv;
                }
        lds_fence();

        // ================= layer 2 (bfW pre-loaded) =================
#pragma unroll
        for (int mt = 0; mt < 2; ++mt)
#pragma unroll
            for (int nt = 0; nt < 4; ++nt) acc[mt][nt] = zero4;
#pragma unroll
        for (int ktl = 0; ktl < 2; ++ktl)
#pragma unroll
            for (int mt = 0; mt < 2; ++mt) {
                f16x8 af = *(const f16x8*)(&Ah[(mt * 16 + col) * 72 + ktl * 32 + q * 8]);
#pragma unroll
                for (int nt = 0; nt < 4; ++nt)
                    acc[mt][nt] = __builtin_amdgcn_mfma_f32_16x16x32_f16(af, bfW[ktl * 4 + nt], acc[mt][nt], 0, 0, 0);
            }

        // ---- prefetch W3 fragments while L2 MFMAs drain ----
#pragma unroll
        for (int f = 0; f < 8; ++f)
            bfW[f] = *(const f16x8*)(wfrag + W3_OFF + ((size_t)(f * 64 + l)) * 8);

        lds_fence();   // L2's ds_reads done -> safe to overwrite Ah
#pragma unroll
        for (int nt = 0; nt < 4; ++nt) bb[nt] = b2[nt * 16 + col];
#pragma unroll
        for (int mt = 0; mt < 2; ++mt)
#pragma unroll
            for (int nt = 0; nt < 4; ++nt)
#pragma unroll
                for (int r = 0; r < 4; ++r) {
                    float hv = fmaxf(acc[mt][nt][r] + bb[nt], 0.0f);
                    Ah[(mt * 16 + q * 4 + r) * 72 + nt * 16 + col] = (_Float16)hv;
                }
        lds_fence();

        // ================= layer 3 =================
#pragma unroll
        for (int mt = 0; mt < 2; ++mt)
#pragma unroll
            for (int nt = 0; nt < 4; ++nt) acc[mt][nt] = zero4;
#pragma unroll
        for (int ktl = 0; ktl < 2; ++ktl)
#pragma unroll
            for (int mt = 0; mt < 2; ++mt) {
                f16x8 af = *(const f16x8*)(&Ah[(mt * 16 + col) * 72 + ktl * 32 + q * 8]);
#pragma unroll
                for (int nt = 0; nt < 4; ++nt)
                    acc[mt][nt] = __builtin_amdgcn_mfma_f32_16x16x32_f16(af, bfW[ktl * 4 + nt], acc[mt][nt], 0, 0, 0);
            }

        // ================= layer 4: relu + dot(W4) + 16-lane shfl reduction =================
        float b3v[4], w4v[4];
#pragma unroll
        for (int nt = 0; nt < 4; ++nt) {
            b3v[nt] = b3[nt * 16 + col];
            w4v[nt] = W4[nt * 16 + col];
        }
        const float b4v = b4[0];
#pragma unroll
        for (int mt = 0; mt < 2; ++mt)
#pragma unroll
            for (int r = 0; r < 4; ++r) {
                float p = 0.0f;
#pragma unroll
                for (int nt = 0; nt < 4; ++nt)
                    p = fmaf(fmaxf(acc[mt][nt][r] + b3v[nt], 0.0f), w4v[nt], p);
                p += __shfl_xor(p, 1);
                p += __shfl_xor(p, 2);
                p += __shfl_xor(p, 4);
                p += __shfl_xor(p, 8);
                if (col == 0) out[base + mt * 16 + q * 4 + r] = p + b4v;
            }
    }
}

// ---------------- fallback: verified R1 pure-VALU kernel ----------------
__global__ __launch_bounds__(64, 2) void decoder_valu(
    const float* __restrict__ feats, const float* __restrict__ points,
    const float* __restrict__ Kmat, const float* __restrict__ Rt,
    const float* __restrict__ Bg,
    const float* __restrict__ W1, const float* __restrict__ b1,
    const float* __restrict__ W2, const float* __restrict__ b2,
    const float* __restrict__ W3, const float* __restrict__ b3,
    const float* __restrict__ W4, const float* __restrict__ b4,
    float* __restrict__ out) {
    __shared__ float hbuf[64 * 65];
    const int tid = threadIdx.x;
    const int b   = blockIdx.x / (NPTS / 64);
    const int gid = blockIdx.x * 64 + tid;
    const float px = points[(size_t)gid * 3 + 0];
    const float py = points[(size_t)gid * 3 + 1];
    const float pz = points[(size_t)gid * 3 + 2];
    const float* rt = Rt + b * 12;
    const float* km = Kmat + b * 9;
    float cx = rt[0] * px + rt[1] * py + rt[2]  * pz + rt[3];
    float cy = rt[4] * px + rt[5] * py + rt[6]  * pz + rt[7];
    float cz = rt[8] * px + rt[9] * py + rt[10] * pz + rt[11];
    float ix = km[0] * cx + km[1] * cy + km[2] * cz;
    float iy = km[3] * cx + km[4] * cy + km[5] * cz;
    float iz = km[6] * cx + km[7] * cy + km[8] * cz;
    float z  = iz + 1e-8f;
    float u  = ix / z, v = iy / z;
    float valid = (iz > 0.0f) ? 1.0f : 0.0f;
    float u_norm = (2.0f * u + 1.0f) / (float)IMG_W - 1.0f;
    float v_norm = (2.0f * v + 1.0f) / (float)IMG_H - 1.0f;
    float x = ((u_norm + 1.0f) * (float)IMG_W - 1.0f) * 0.5f;
    float y = ((v_norm + 1.0f) * (float)IMG_H - 1.0f) * 0.5f;
    float x0f = floorf(x), y0f = floorf(y);
    float wx1 = x - x0f, wy1 = y - y0f;
    float wx0 = 1.0f - wx1, wy0 = 1.0f - wy1;
    int x0 = (int)x0f, y0 = (int)y0f;
    int x1 = x0 + 1, y1 = y0 + 1;
    int x0c = x0 < 0 ? 0 : (x0 > IMG_W - 1 ? IMG_W - 1 : x0);
    int x1c = x1 < 0 ? 0 : (x1 > IMG_W - 1 ? IMG_W - 1 : x1);
    int y0c = y0 < 0 ? 0 : (y0 > IMG_H - 1 ? IMG_H - 1 : y0);
    int y1c = y1 < 0 ? 0 : (y1 > IMG_H - 1 ? IMG_H - 1 : y1);
    float mx0 = (x0 >= 0 && x0 < IMG_W) ? 1.0f : 0.0f;
    float mx1 = (x1 >= 0 && x1 < IMG_W) ? 1.0f : 0.0f;
    float my0 = (y0 >= 0 && y0 < IMG_H) ? 1.0f : 0.0f;
    float my1 = (y1 >= 0 && y1 < IMG_H) ? 1.0f : 0.0f;
    float w00 = wx0 * wy0 * mx0 * my0 * valid;
    float w10 = wx1 * wy0 * mx1 * my0 * valid;
    float w01 = wx0 * wy1 * mx0 * my1 * valid;
    float w11 = wx1 * wy1 * mx1 * my1 * valid;
    float h[HDIM];
#pragma unroll
    for (int j = 0; j < HDIM; ++j) h[j] = b1[j];
    const float* fb = feats + (size_t)b * FDIM * NPIX;
    const int p00 = y0c * IMG_W + x0c, p10 = y0c * IMG_W + x1c;
    const int p01 = y1c * IMG_W + x0c, p11 = y1c * IMG_W + x1c;
#pragma unroll 1
    for (int c = 0; c < FDIM; ++c) {
        const float* fp = fb + (size_t)c * NPIX;
        float fv = w00 * fp[p00] + w10 * fp[p10] + w01 * fp[p01] + w11 * fp[p11];
        const float* wr = W1 + (size_t)c * HDIM;
#pragma unroll
        for (int j = 0; j < HDIM; ++j) h[j] = fmaf(fv, wr[j], h[j]);
    }
#pragma unroll 1
    for (int m = 0; m < MSIZE; ++m) {
        float t = Bg[m * 3 + 0] * px + Bg[m * 3 + 1] * py + Bg[m * 3 + 2] * pz;
        float tf = t - floorf(t);
        float s = __builtin_amdgcn_sinf(tf);
        float c = __builtin_amdgcn_cosf(tf);
        const float* wsn = W1 + (size_t)(FDIM + m) * HDIM;
        const float* wcs = W1 + (size_t)(FDIM + MSIZE + m) * HDIM;
#pragma unroll
        for (int j = 0; j < HDIM; ++j)
            h[j] = fmaf(s, wsn[j], fmaf(c, wcs[j], h[j]));
    }
    float* myh = &hbuf[tid * 65];
#pragma unroll
    for (int j = 0; j < HDIM; ++j) myh[j] = fmaxf(h[j], 0.0f);
    float h2[HDIM];
#pragma unroll
    for (int j = 0; j < HDIM; ++j) h2[j] = b2[j];
#pragma unroll 1
    for (int i = 0; i < HDIM; ++i) {
        float hi = myh[i];
        const float* wr = W2 + (size_t)i * HDIM;
#pragma unroll
        for (int j = 0; j < HDIM; ++j) h2[j] = fmaf(hi, wr[j], h2[j]);
    }
#pragma unroll
    for (int j = 0; j < HDIM; ++j) myh[j] = fmaxf(h2[j], 0.0f);
#pragma unroll
    for (int j = 0; j < HDIM; ++j) h[j] = b3[j];
#pragma unroll 1
    for (int i = 0; i < HDIM; ++i) {
        float hi = myh[i];
        const float* wr = W3 + (size_t)i * HDIM;
#pragma unroll
        for (int j = 0; j < HDIM; ++j) h[j] = fmaf(hi, wr[j], h[j]);
    }
    float acc = b4[0];
#pragma unroll
    for (int j = 0; j < HDIM; ++j) acc = fmaf(fmaxf(h[j], 0.0f), W4[j], acc);
    out[gid] = acc;
}

extern "C" void kernel_launch(void* const* d_in, const int* in_sizes, int n_in,
                              void* d_out, int out_size, void* d_ws, size_t ws_size,
                              hipStream_t stream) {
    const float* feats = (const float*)d_in[0];
    const float* pts   = (const float*)d_in[1];
    const float* k     = (const float*)d_in[2];
    const float* rt    = (const float*)d_in[3];
    const float* Bg    = (const float*)d_in[4];
    const float* W1    = (const float*)d_in[5];
    const float* b1    = (const float*)d_in[6];
    const float* W2    = (const float*)d_in[7];
    const float* b2    = (const float*)d_in[8];
    const float* W3    = (const float*)d_in[9];
    const float* b3    = (const float*)d_in[10];
    const float* W4    = (const float*)d_in[11];
    const float* b4    = (const float*)d_in[12];
    float* out = (float*)d_out;

    const size_t ftBytes = (size_t)NB * NPIX * FDIM * sizeof(_Float16);

    if (ws_size >= FT_BYTE_OFF + ftBytes) {
        _Float16* wf = (_Float16*)d_ws;
        _Float16* ft = (_Float16*)((char*)d_ws + FT_BYTE_OFF);
        prep_kernel<<<TR16_BLOCKS + 12, 256, 0, stream>>>(feats, W1, W2, W3, wf);
        decoder_mfma4<<<NB * NPTS / 128, 256, 0, stream>>>(ft, pts, k, rt, Bg, wf,
                                                           b1, b2, b3, W4, b4, out);
    } else {
        decoder_valu<<<NB * NPTS / 64, 64, 0, stream>>>(feats, pts, k, rt, Bg,
                                                        W1, b1, W2, b2, W3, b3, W4, b4, out);
    }
}

// Round 10
// 173.968 us; speedup vs baseline: 3.0946x; 1.0576x over previous
//
#include <hip/hip_runtime.h>

#define FDIM 128
#define HDIM 64
#define MSIZE 64
#define IMG_W 56
#define IMG_H 56
#define NPIX (IMG_W * IMG_H)
#define NB 8
#define NPTS 65536

typedef _Float16 f16x8 __attribute__((ext_vector_type(8)));
typedef __fp16 hf16x2 __attribute__((ext_vector_type(2)));   // return type of cvt_pkrtz
typedef float f32x4 __attribute__((ext_vector_type(4)));

// d_ws layout:
//   [0, 32768)       : W1 fragments fp16 (8kt*4nt*64lane*8)
//   [32768, 40960)   : W2 fragments
//   [40960, 49152)   : W3 fragments
//   [49152, 49920)   : Bg SoA  (Bx[64], By[64], Bz[64] fp32)
//   [50176, +6.4MB)  : transposed features (B, H*W, C) fp16
#define W2_OFF 16384   // in halves
#define W3_OFF 20480
#define BG_OFF 49152   // bytes
#define FT_BYTE_OFF 50176
#define TR16_BLOCKS (NPIX / 16 * NB)   // 1568

// wave-local LDS fence: orders this wave's ds ops without the full
// vmcnt(0)+barrier drain __syncthreads forces.
__device__ __forceinline__ void lds_fence() {
    __asm__ volatile("s_waitcnt lgkmcnt(0)" ::: "memory");
}

// ---- fused prep: transpose + weight pack + Bg SoA ----
__global__ __launch_bounds__(256) void prep_kernel(const float* __restrict__ in,
                                                   const float* __restrict__ W1,
                                                   const float* __restrict__ W2,
                                                   const float* __restrict__ W3,
                                                   const float* __restrict__ Bg,
                                                   _Float16* __restrict__ ws) {
    if (blockIdx.x < TR16_BLOCKS) {
        __shared__ float tile[16][133];
        _Float16* out = ws + FT_BYTE_OFF / 2;
        const int b = blockIdx.x / (NPIX / 16);
        const int pbase = (blockIdx.x % (NPIX / 16)) * 16;
        const int t = threadIdx.x;
        const float* src = in + (size_t)b * FDIM * NPIX;
        _Float16*    dst = out + (size_t)b * NPIX * FDIM;
        const int pq = t & 3;
        const int ch = t >> 2;
#pragma unroll
        for (int it = 0; it < 2; ++it) {
            const int c = it * 64 + ch;
            const float4 v = *(const float4*)(src + (size_t)c * NPIX + pbase + pq * 4);
            tile[pq * 4 + 0][c] = v.x;
            tile[pq * 4 + 1][c] = v.y;
            tile[pq * 4 + 2][c] = v.z;
            tile[pq * 4 + 3][c] = v.w;
        }
        __syncthreads();
        const int px = t >> 4;
        const int hk = (t & 15) * 8;
        union { f16x8 v; hf16x2 h[4]; } hv;
#pragma unroll
        for (int j = 0; j < 4; ++j)
            hv.h[j] = __builtin_amdgcn_cvt_pkrtz(tile[px][hk + 2 * j], tile[px][hk + 2 * j + 1]);
        *(f16x8*)(dst + (size_t)(pbase + px) * FDIM + hk) = hv.v;
    } else if (blockIdx.x < TR16_BLOCKS + 12) {
        const int t = (blockIdx.x - TR16_BLOCKS) * 256 + threadIdx.x;  // 0..3071
        const int l = t & 63;
        const int q = l >> 4;
        const int col = l & 15;
        const int frag = t >> 6;  // 0..47
        if (frag < 32) {
            const int kt = frag >> 2, nt = frag & 3;
#pragma unroll
            for (int j = 0; j < 8; ++j) {
                int k = kt * 32 + q * 8 + j;
                int row = (k < 128) ? k : (128 + (k & 1) * 64 + ((k - 128) >> 1));
                ws[((size_t)(frag * 64 + l)) * 8 + j] = (_Float16)W1[row * HDIM + nt * 16 + col];
            }
        } else if (frag < 40) {
            const int f2 = frag - 32;
            const int kt = f2 >> 2, nt = f2 & 3;
#pragma unroll
            for (int j = 0; j < 8; ++j) {
                int row = kt * 32 + q * 8 + j;
                ws[W2_OFF + ((size_t)(f2 * 64 + l)) * 8 + j] = (_Float16)W2[row * HDIM + nt * 16 + col];
            }
        } else {
            const int f3 = frag - 40;
            const int kt = f3 >> 2, nt = f3 & 3;
#pragma unroll
            for (int j = 0; j < 8; ++j) {
                int row = kt * 32 + q * 8 + j;
                ws[W3_OFF + ((size_t)(f3 * 64 + l)) * 8 + j] = (_Float16)W3[row * HDIM + nt * 16 + col];
            }
        }
    } else {
        // Bg -> SoA
        const int t = threadIdx.x;
        if (t < MSIZE) {
            float* bgs = (float*)((char*)ws + BG_OFF);
            bgs[t]       = Bg[t * 3 + 0];
            bgs[64 + t]  = Bg[t * 3 + 1];
            bgs[128 + t] = Bg[t * 3 + 2];
        }
    }
}

// -------- decoder v5: W1 fragments staged in LDS; B-frag reads = ds_read_b128 --------
__global__ __launch_bounds__(256, 3) void decoder_mfma5(
    const _Float16* __restrict__ ft,   // (B, HW, C) fp16
    const float* __restrict__ points,
    const float* __restrict__ Kmat, const float* __restrict__ Rt,
    const _Float16* __restrict__ wfrag,
    const float* __restrict__ b1, const float* __restrict__ b2,
    const float* __restrict__ b3,
    const float* __restrict__ W4, const float* __restrict__ b4,
    float* __restrict__ out) {
    __shared__ _Float16 w1l[16384];          // 32768 B: W1 fragments
    __shared__ _Float16 lds[4 * 32 * 72];    // 18432 B: per-wave A/H tiles
    const int tid = threadIdx.x;
    const int wid = tid >> 6;
    const int l   = tid & 63;
    const int q   = l >> 4;
    const int col = l & 15;
    const int b    = blockIdx.x & 7;             // XCD swizzle
    const int grp  = blockIdx.x >> 3;            // 0..511
    const int base = b * NPTS + grp * 128 + wid * 32;
    _Float16* Ah = lds + wid * 32 * 72;
    const float* bgs = (const float*)((const char*)wfrag + BG_OFF);

    // ---- stage W1 fragments to LDS (coalesced, 16B x 8 per thread) ----
#pragma unroll
    for (int i = 0; i < 8; ++i)
        ((f16x8*)w1l)[i * 256 + tid] = ((const f16x8*)wfrag)[i * 256 + tid];

    // ---- ALL lanes: projection for point base + (l&31) ----
    const int gid = base + (l & 31);
    const float px = points[(size_t)gid * 3 + 0];
    const float py = points[(size_t)gid * 3 + 1];
    const float pz = points[(size_t)gid * 3 + 2];
    const float* rt = Rt + b * 12;
    const float* km = Kmat + b * 9;
    float cx = rt[0] * px + rt[1] * py + rt[2]  * pz + rt[3];
    float cy = rt[4] * px + rt[5] * py + rt[6]  * pz + rt[7];
    float cz = rt[8] * px + rt[9] * py + rt[10] * pz + rt[11];
    float ix = km[0] * cx + km[1] * cy + km[2] * cz;
    float iy = km[3] * cx + km[4] * cy + km[5] * cz;
    float iz = km[6] * cx + km[7] * cy + km[8] * cz;
    float z  = iz + 1e-8f;
    float u  = ix / z;
    float v  = iy / z;
    float valid = (iz > 0.0f) ? 1.0f : 0.0f;
    float u_norm = (2.0f * u + 1.0f) / (float)IMG_W - 1.0f;
    float v_norm = (2.0f * v + 1.0f) / (float)IMG_H - 1.0f;
    float x = ((u_norm + 1.0f) * (float)IMG_W - 1.0f) * 0.5f;
    float y = ((v_norm + 1.0f) * (float)IMG_H - 1.0f) * 0.5f;
    float x0f = floorf(x), y0f = floorf(y);
    float wx1 = x - x0f, wy1 = y - y0f;
    float wx0 = 1.0f - wx1, wy0 = 1.0f - wy1;
    int x0 = (int)x0f, y0 = (int)y0f;
    int x1 = x0 + 1, y1 = y0 + 1;
    int x0c = x0 < 0 ? 0 : (x0 > IMG_W - 1 ? IMG_W - 1 : x0);
    int x1c = x1 < 0 ? 0 : (x1 > IMG_W - 1 ? IMG_W - 1 : x1);
    int y0c = y0 < 0 ? 0 : (y0 > IMG_H - 1 ? IMG_H - 1 : y0);
    int y1c = y1 < 0 ? 0 : (y1 > IMG_H - 1 ? IMG_H - 1 : y1);
    float mx0 = (x0 >= 0 && x0 < IMG_W) ? 1.0f : 0.0f;
    float mx1 = (x1 >= 0 && x1 < IMG_W) ? 1.0f : 0.0f;
    float my0 = (y0 >= 0 && y0 < IMG_H) ? 1.0f : 0.0f;
    float my1 = (y1 >= 0 && y1 < IMG_H) ? 1.0f : 0.0f;
    const int pb = b * NPIX;
    float r_w00 = wx0 * wy0 * mx0 * my0 * valid;
    float r_w10 = wx1 * wy0 * mx1 * my0 * valid;
    float r_w01 = wx0 * wy1 * mx0 * my1 * valid;
    float r_w11 = wx1 * wy1 * mx1 * my1 * valid;
    int r_i00 = (pb + y0c * IMG_W + x0c) * FDIM;
    int r_i10 = (pb + y0c * IMG_W + x1c) * FDIM;
    int r_i01 = (pb + y1c * IMG_W + x0c) * FDIM;
    int r_i11 = (pb + y1c * IMG_W + x1c) * FDIM;

    // ---- broadcast records via shfl ----
    float wv0[2], wv1[2], wv2[2], wv3[2];
    int   iv0[2], iv1[2], iv2[2], iv3[2];
    float qx[2], qy[2], qz[2];
#pragma unroll
    for (int mt = 0; mt < 2; ++mt) {
        const int src = mt * 16 + col;
        wv0[mt] = __shfl(r_w00, src);
        wv1[mt] = __shfl(r_w10, src);
        wv2[mt] = __shfl(r_w01, src);
        wv3[mt] = __shfl(r_w11, src);
        iv0[mt] = __shfl(r_i00, src);
        iv1[mt] = __shfl(r_i10, src);
        iv2[mt] = __shfl(r_i01, src);
        iv3[mt] = __shfl(r_i11, src);
        qx[mt]  = __shfl(px, src);
        qy[mt]  = __shfl(py, src);
        qz[mt]  = __shfl(pz, src);
    }

    __syncthreads();   // w1l staged (once per block)

    const f32x4 zero4 = {0.0f, 0.0f, 0.0f, 0.0f};
    f32x4 acc[2][4];
#pragma unroll
    for (int mt = 0; mt < 2; ++mt)
#pragma unroll
        for (int nt = 0; nt < 4; ++nt) acc[mt][nt] = zero4;

    // ---- pre-issue corner-load groups s=0 and s=1 (depth-2) ----
    const int co0 = q * 8;
    f16x8 a00 = *(const f16x8*)(ft + iv0[0] + co0);
    f16x8 a10 = *(const f16x8*)(ft + iv1[0] + co0);
    f16x8 a01 = *(const f16x8*)(ft + iv2[0] + co0);
    f16x8 a11 = *(const f16x8*)(ft + iv3[0] + co0);
    const int co1 = 32 + q * 8;
    f16x8 e00 = *(const f16x8*)(ft + iv0[0] + co1);
    f16x8 e10 = *(const f16x8*)(ft + iv1[0] + co1);
    f16x8 e01 = *(const f16x8*)(ft + iv2[0] + co1);
    f16x8 e11 = *(const f16x8*)(ft + iv3[0] + co1);

    // ====== Phase F: Fourier k-tiles 4..7; Bg SoA dwordx4 loads; B-frags from LDS ======
#pragma unroll
    for (int ktf = 0; ktf < 4; ++ktf) {
        const f32x4 bgx = *(const f32x4*)(bgs + ktf * 16 + q * 4);
        const f32x4 bgy = *(const f32x4*)(bgs + 64 + ktf * 16 + q * 4);
        const f32x4 bgz = *(const f32x4*)(bgs + 128 + ktf * 16 + q * 4);
        f16x8 bf[4];
#pragma unroll
        for (int nt = 0; nt < 4; ++nt)
            bf[nt] = *(const f16x8*)(w1l + ((size_t)(((4 + ktf) * 4 + nt) * 64 + l)) * 8);
#pragma unroll
        for (int mt = 0; mt < 2; ++mt) {
            union { f16x8 v; hf16x2 h[4]; } af;
#pragma unroll
            for (int i = 0; i < 4; ++i) {
                float t = bgx[i] * qx[mt] + bgy[i] * qy[mt] + bgz[i] * qz[mt];
                float tf = __builtin_amdgcn_fractf(t);
                af.h[i] = __builtin_amdgcn_cvt_pkrtz(__builtin_amdgcn_sinf(tf),
                                                     __builtin_amdgcn_cosf(tf));
            }
#pragma unroll
            for (int nt = 0; nt < 4; ++nt)
                acc[mt][nt] = __builtin_amdgcn_mfma_f32_16x16x32_f16(af.v, bf[nt], acc[mt][nt], 0, 0, 0);
        }
    }

    // ====== Phase I: 8 groups, depth-2 rolling prefetch, packed-fp16 blend ======
    _Float16 wh[2][4];
#pragma unroll
    for (int mt = 0; mt < 2; ++mt) {
        wh[mt][0] = (_Float16)wv0[mt]; wh[mt][1] = (_Float16)wv1[mt];
        wh[mt][2] = (_Float16)wv2[mt]; wh[mt][3] = (_Float16)wv3[mt];
    }
#pragma unroll
    for (int s = 0; s < 8; ++s) {
        const int mt = s >> 2;
        f16x8 t00, t10, t01, t11;
        if (s < 6) {
            const int nmt = (s + 2) >> 2, nktg = (s + 2) & 3;
            const int co = nktg * 32 + q * 8;
            t00 = *(const f16x8*)(ft + iv0[nmt] + co);
            t10 = *(const f16x8*)(ft + iv1[nmt] + co);
            t01 = *(const f16x8*)(ft + iv2[nmt] + co);
            t11 = *(const f16x8*)(ft + iv3[nmt] + co);
        }
        f16x8 af = a00 * wh[mt][0] + a10 * wh[mt][1] + a01 * wh[mt][2] + a11 * wh[mt][3];
        const int ktg = s & 3;
#pragma unroll
        for (int nt = 0; nt < 4; ++nt) {
            f16x8 bf = *(const f16x8*)(w1l + ((size_t)((ktg * 4 + nt) * 64 + l)) * 8);
            acc[mt][nt] = __builtin_amdgcn_mfma_f32_16x16x32_f16(af, bf, acc[mt][nt], 0, 0, 0);
        }
        a00 = e00; a10 = e10; a01 = e01; a11 = e11;
        e00 = t00; e10 = t10; e01 = t01; e11 = t11;
    }

    // ---- prefetch W2 fragments (global; off critical path) ----
    f16x8 bfW[8];
#pragma unroll
    for (int f = 0; f < 8; ++f)
        bfW[f] = *(const f16x8*)(wfrag + W2_OFF + ((size_t)(f * 64 + l)) * 8);

    // ---- L1 epilogue: +b1, relu, store h1 in A-layout fp16 ----
    float bb[4];
#pragma unroll
    for (int nt = 0; nt < 4; ++nt) bb[nt] = b1[nt * 16 + col];
#pragma unroll
    for (int mt = 0; mt < 2; ++mt)
#pragma unroll
        for (int nt = 0; nt < 4; ++nt)
#pragma unroll
            for (int r = 0; r < 4; ++r) {
                float hv = fmaxf(acc[mt][nt][r] + bb[nt], 0.0f);
                Ah[(mt * 16 + q * 4 + r) * 72 + nt * 16 + col] = (_Float16)hv;
            }
    lds_fence();

    // ================= layer 2 (bfW pre-loaded) =================
#pragma unroll
    for (int mt = 0; mt < 2; ++mt)
#pragma unroll
        for (int nt = 0; nt < 4; ++nt) acc[mt][nt] = zero4;
#pragma unroll
    for (int ktl = 0; ktl < 2; ++ktl)
#pragma unroll
        for (int mt = 0; mt < 2; ++mt) {
            f16x8 af = *(const f16x8*)(&Ah[(mt * 16 + col) * 72 + ktl * 32 + q * 8]);
#pragma unroll
            for (int nt = 0; nt < 4; ++nt)
                acc[mt][nt] = __builtin_amdgcn_mfma_f32_16x16x32_f16(af, bfW[ktl * 4 + nt], acc[mt][nt], 0, 0, 0);
        }

    // ---- prefetch W3 while L2 MFMAs drain ----
#pragma unroll
    for (int f = 0; f < 8; ++f)
        bfW[f] = *(const f16x8*)(wfrag + W3_OFF + ((size_t)(f * 64 + l)) * 8);

    lds_fence();
#pragma unroll
    for (int nt = 0; nt < 4; ++nt) bb[nt] = b2[nt * 16 + col];
#pragma unroll
    for (int mt = 0; mt < 2; ++mt)
#pragma unroll
        for (int nt = 0; nt < 4; ++nt)
#pragma unroll
            for (int r = 0; r < 4; ++r) {
                float hv = fmaxf(acc[mt][nt][r] + bb[nt], 0.0f);
                Ah[(mt * 16 + q * 4 + r) * 72 + nt * 16 + col] = (_Float16)hv;
            }
    lds_fence();

    // ================= layer 3 =================
#pragma unroll
    for (int mt = 0; mt < 2; ++mt)
#pragma unroll
        for (int nt = 0; nt < 4; ++nt) acc[mt][nt] = zero4;
#pragma unroll
    for (int ktl = 0; ktl < 2; ++ktl)
#pragma unroll
        for (int mt = 0; mt < 2; ++mt) {
            f16x8 af = *(const f16x8*)(&Ah[(mt * 16 + col) * 72 + ktl * 32 + q * 8]);
#pragma unroll
            for (int nt = 0; nt < 4; ++nt)
                acc[mt][nt] = __builtin_amdgcn_mfma_f32_16x16x32_f16(af, bfW[ktl * 4 + nt], acc[mt][nt], 0, 0, 0);
        }

    // ================= layer 4: relu + dot(W4) + 16-lane shfl reduction =================
    float b3v[4], w4v[4];
#pragma unroll
    for (int nt = 0; nt < 4; ++nt) {
        b3v[nt] = b3[nt * 16 + col];
        w4v[nt] = W4[nt * 16 + col];
    }
    const float b4v = b4[0];
#pragma unroll
    for (int mt = 0; mt < 2; ++mt)
#pragma unroll
        for (int r = 0; r < 4; ++r) {
            float p = 0.0f;
#pragma unroll
            for (int nt = 0; nt < 4; ++nt)
                p = fmaf(fmaxf(acc[mt][nt][r] + b3v[nt], 0.0f), w4v[nt], p);
            p += __shfl_xor(p, 1);
            p += __shfl_xor(p, 2);
            p += __shfl_xor(p, 4);
            p += __shfl_xor(p, 8);
            if (col == 0) out[base + mt * 16 + q * 4 + r] = p + b4v;
        }
}

// ---------------- fallback: verified R1 pure-VALU kernel ----------------
__global__ __launch_bounds__(64, 2) void decoder_valu(
    const float* __restrict__ feats, const float* __restrict__ points,
    const float* __restrict__ Kmat, const float* __restrict__ Rt,
    const float* __restrict__ Bg,
    const float* __restrict__ W1, const float* __restrict__ b1,
    const float* __restrict__ W2, const float* __restrict__ b2,
    const float* __restrict__ W3, const float* __restrict__ b3,
    const float* __restrict__ W4, const float* __restrict__ b4,
    float* __restrict__ out) {
    __shared__ float hbuf[64 * 65];
    const int tid = threadIdx.x;
    const int b   = blockIdx.x / (NPTS / 64);
    const int gid = blockIdx.x * 64 + tid;
    const float px = points[(size_t)gid * 3 + 0];
    const float py = points[(size_t)gid * 3 + 1];
    const float pz = points[(size_t)gid * 3 + 2];
    const float* rt = Rt + b * 12;
    const float* km = Kmat + b * 9;
    float cx = rt[0] * px + rt[1] * py + rt[2]  * pz + rt[3];
    float cy = rt[4] * px + rt[5] * py + rt[6]  * pz + rt[7];
    float cz = rt[8] * px + rt[9] * py + rt[10] * pz + rt[11];
    float ix = km[0] * cx + km[1] * cy + km[2] * cz;
    float iy = km[3] * cx + km[4] * cy + km[5] * cz;
    float iz = km[6] * cx + km[7] * cy + km[8] * cz;
    float z  = iz + 1e-8f;
    float u  = ix / z, v = iy / z;
    float valid = (iz > 0.0f) ? 1.0f : 0.0f;
    float u_norm = (2.0f * u + 1.0f) / (float)IMG_W - 1.0f;
    float v_norm = (2.0f * v + 1.0f) / (float)IMG_H - 1.0f;
    float x = ((u_norm + 1.0f) * (float)IMG_W - 1.0f) * 0.5f;
    float y = ((v_norm + 1.0f) * (float)IMG_H - 1.0f) * 0.5f;
    float x0f = floorf(x), y0f = floorf(y);
    float wx1 = x - x0f, wy1 = y - y0f;
    float wx0 = 1.0f - wx1, wy0 = 1.0f - wy1;
    int x0 = (int)x0f, y0 = (int)y0f;
    int x1 = x0 + 1, y1 = y0 + 1;
    int x0c = x0 < 0 ? 0 : (x0 > IMG_W - 1 ? IMG_W - 1 : x0);
    int x1c = x1 < 0 ? 0 : (x1 > IMG_W - 1 ? IMG_W - 1 : x1);
    int y0c = y0 < 0 ? 0 : (y0 > IMG_H - 1 ? IMG_H - 1 : y0);
    int y1c = y1 < 0 ? 0 : (y1 > IMG_H - 1 ? IMG_H - 1 : y1);
    float mx0 = (x0 >= 0 && x0 < IMG_W) ? 1.0f : 0.0f;
    float mx1 = (x1 >= 0 && x1 < IMG_W) ? 1.0f : 0.0f;
    float my0 = (y0 >= 0 && y0 < IMG_H) ? 1.0f : 0.0f;
    float my1 = (y1 >= 0 && y1 < IMG_H) ? 1.0f : 0.0f;
    float w00 = wx0 * wy0 * mx0 * my0 * valid;
    float w10 = wx1 * wy0 * mx1 * my0 * valid;
    float w01 = wx0 * wy1 * mx0 * my1 * valid;
    float w11 = wx1 * wy1 * mx1 * my1 * valid;
    float h[HDIM];
#pragma unroll
    for (int j = 0; j < HDIM; ++j) h[j] = b1[j];
    const float* fb = feats + (size_t)b * FDIM * NPIX;
    const int p00 = y0c * IMG_W + x0c, p10 = y0c * IMG_W + x1c;
    const int p01 = y1c * IMG_W + x0c, p11 = y1c * IMG_W + x1c;
#pragma unroll 1
    for (int c = 0; c < FDIM; ++c) {
        const float* fp = fb + (size_t)c * NPIX;
        float fv = w00 * fp[p00] + w10 * fp[p10] + w01 * fp[p01] + w11 * fp[p11];
        const float* wr = W1 + (size_t)c * HDIM;
#pragma unroll
        for (int j = 0; j < HDIM; ++j) h[j] = fmaf(fv, wr[j], h[j]);
    }
#pragma unroll 1
    for (int m = 0; m < MSIZE; ++m) {
        float t = Bg[m * 3 + 0] * px + Bg[m * 3 + 1] * py + Bg[m * 3 + 2] * pz;
        float tf = t - floorf(t);
        float s = __builtin_amdgcn_sinf(tf);
        float c = __builtin_amdgcn_cosf(tf);
        const float* wsn = W1 + (size_t)(FDIM + m) * HDIM;
        const float* wcs = W1 + (size_t)(FDIM + MSIZE + m) * HDIM;
#pragma unroll
        for (int j = 0; j < HDIM; ++j)
            h[j] = fmaf(s, wsn[j], fmaf(c, wcs[j], h[j]));
    }
    float* myh = &hbuf[tid * 65];
#pragma unroll
    for (int j = 0; j < HDIM; ++j) myh[j] = fmaxf(h[j], 0.0f);
    float h2[HDIM];
#pragma unroll
    for (int j = 0; j < HDIM; ++j) h2[j] = b2[j];
#pragma unroll 1
    for (int i = 0; i < HDIM; ++i) {
        float hi = myh[i];
        const float* wr = W2 + (size_t)i * HDIM;
#pragma unroll
        for (int j = 0; j < HDIM; ++j) h2[j] = fmaf(hi, wr[j], h2[j]);
    }
#pragma unroll
    for (int j = 0; j < HDIM; ++j) myh[j] = fmaxf(h2[j], 0.0f);
#pragma unroll
    for (int j = 0; j < HDIM; ++j) h[j] = b3[j];
#pragma unroll 1
    for (int i = 0; i < HDIM; ++i) {
        float hi = myh[i];
        const float* wr = W3 + (size_t)i * HDIM;
#pragma unroll
        for (int j = 0; j < HDIM; ++j) h[j] = fmaf(hi, wr[j], h[j]);
    }
    float acc = b4[0];
#pragma unroll
    for (int j = 0; j < HDIM; ++j) acc = fmaf(fmaxf(h[j], 0.0f), W4[j], acc);
    out[gid] = acc;
}

extern "C" void kernel_launch(void* const* d_in, const int* in_sizes, int n_in,
                              void* d_out, int out_size, void* d_ws, size_t ws_size,
                              hipStream_t stream) {
    const float* feats = (const float*)d_in[0];
    const float* pts   = (const float*)d_in[1];
    const float* k     = (const float*)d_in[2];
    const float* rt    = (const float*)d_in[3];
    const float* Bg    = (const float*)d_in[4];
    const float* W1    = (const float*)d_in[5];
    const float* b1    = (const float*)d_in[6];
    const float* W2    = (const float*)d_in[7];
    const float* b2    = (const float*)d_in[8];
    const float* W3    = (const float*)d_in[9];
    const float* b3    = (const float*)d_in[10];
    const float* W4    = (const float*)d_in[11];
    const float* b4    = (const float*)d_in[12];
    float* out = (float*)d_out;

    const size_t ftBytes = (size_t)NB * NPIX * FDIM * sizeof(_Float16);

    if (ws_size >= FT_BYTE_OFF + ftBytes) {
        _Float16* wf = (_Float16*)d_ws;
        _Float16* ft = (_Float16*)((char*)d_ws + FT_BYTE_OFF);
        prep_kernel<<<TR16_BLOCKS + 13, 256, 0, stream>>>(feats, W1, W2, W3, Bg, wf);
        decoder_mfma5<<<NB * NPTS / 128, 256, 0, stream>>>(ft, pts, k, rt, wf,
                                                           b1, b2, b3, W4, b4, out);
    } else {
        decoder_valu<<<NB * NPTS / 64, 64, 0, stream>>>(feats, pts, k, rt, Bg,
                                                        W1, b1, W2, b2, W3, b3, W4, b4, out);
    }
}